// Round 10
// baseline (166.916 us; speedup 1.0000x reference)
//
#include <hip/hip_runtime.h>
#include <hip/hip_bf16.h>
#include <stdint.h>

#define BB 2
#define SS 192
#define DD 256
#define NROW (BB * SS)   // 384
#define NE (NROW * DD)   // 98304

// ---------------- threefry2x32-20 (Random123 / JAX, partitionable) ----------------
__device__ __forceinline__ uint32_t rotl32(uint32_t v, int d) {
  return (v << d) | (v >> (32 - d));
}

__device__ inline void threefry2x32(uint32_t k0, uint32_t k1, uint32_t x0, uint32_t x1,
                                    uint32_t* o0, uint32_t* o1) {
  uint32_t ks2 = k0 ^ k1 ^ 0x1BD11BDAu;
  x0 += k0; x1 += k1;
  const int ra[4] = {13, 15, 26, 6};
  const int rb[4] = {17, 29, 16, 24};
#pragma unroll
  for (int i = 0; i < 4; i++) { x0 += x1; x1 = rotl32(x1, ra[i]); x1 ^= x0; }
  x0 += k1; x1 += ks2 + 1u;
#pragma unroll
  for (int i = 0; i < 4; i++) { x0 += x1; x1 = rotl32(x1, rb[i]); x1 ^= x0; }
  x0 += ks2; x1 += k0 + 2u;
#pragma unroll
  for (int i = 0; i < 4; i++) { x0 += x1; x1 = rotl32(x1, ra[i]); x1 ^= x0; }
  x0 += k0; x1 += k1 + 3u;
#pragma unroll
  for (int i = 0; i < 4; i++) { x0 += x1; x1 = rotl32(x1, rb[i]); x1 ^= x0; }
  x0 += k1; x1 += ks2 + 4u;
#pragma unroll
  for (int i = 0; i < 4; i++) { x0 += x1; x1 = rotl32(x1, ra[i]); x1 ^= x0; }
  x0 += ks2; x1 += k0 + 5u;
  *o0 = x0; *o1 = x1;
}

__device__ inline float erfinv_xla_f32(float x) {
  float w = -log1pf(-x * x);
  float p;
  if (w < 5.0f) {
    w = w - 2.5f;
    p = 2.81022636e-08f;
    p = 3.43273939e-07f + p * w;
    p = -3.5233877e-06f + p * w;
    p = -4.39150654e-06f + p * w;
    p = 0.00021858087f + p * w;
    p = -0.00125372503f + p * w;
    p = -0.00417768164f + p * w;
    p = 0.246640727f + p * w;
    p = 1.50140941f + p * w;
  } else {
    w = sqrtf(w) - 3.0f;
    p = -0.000200214257f;
    p = 0.000100950558f + p * w;
    p = 0.00134934322f + p * w;
    p = -0.00367342844f + p * w;
    p = 0.00573950773f + p * w;
    p = -0.0076224613f + p * w;
    p = 0.00943887047f + p * w;
    p = 1.00167406f + p * w;
    p = 2.83297682f + p * w;
  }
  return p * x;
}

__device__ inline float jax_normal_from_bits(uint32_t bits) {
  float f = __uint_as_float((bits >> 9) | 0x3f800000u) - 1.0f;
  const float lo = -0.99999994f;  // nextafter(-1, 0)
  float u = f * (1.0f - lo) + lo;
  u = fmaxf(lo, u);
  return 1.4142135623730951f * erfinv_xla_f32(u);
}

__device__ inline float jax_normal_at(uint32_t ka, uint32_t kb, uint32_t i) {
  uint32_t o0, o1;
  threefry2x32(ka, kb, 0u, i, &o0, &o1);
  return jax_normal_from_bits(o0 ^ o1);
}

// ---------------- paired reductions (256 threads = 4 waves of 64) ----------------
__device__ inline void blockSum2(double vA, double vB, double* red, int tid,
                                 double& oA, double& oB) {
#pragma unroll
  for (int o = 32; o > 0; o >>= 1) {
    vA += __shfl_down(vA, o, 64);
    vB += __shfl_down(vB, o, 64);
  }
  __syncthreads();
  if ((tid & 63) == 0) { red[tid >> 6] = vA; red[4 + (tid >> 6)] = vB; }
  __syncthreads();
  oA = (red[0] + red[1]) + (red[2] + red[3]);
  oB = (red[4] + red[5]) + (red[6] + red[7]);
}

__device__ inline void reduceS_sum2(const double* aA, const double* aB, double* red,
                                    int tid, double& oA, double& oB) {
  __syncthreads();
  if (tid < 64) {
    double vA = aA[tid] + aA[tid + 64] + aA[tid + 128];
    double vB = aB[tid] + aB[tid + 64] + aB[tid + 128];
#pragma unroll
    for (int o = 32; o > 0; o >>= 1) {
      vA += __shfl_down(vA, o, 64);
      vB += __shfl_down(vB, o, 64);
    }
    if (tid == 0) { red[8] = vA; red[9] = vB; }
  }
  __syncthreads();
  oA = red[8]; oB = red[9];
}

__device__ inline void reduceS_min2(const double* aA, const double* aB, double* red,
                                    int tid, double& oA, double& oB) {
  __syncthreads();
  if (tid < 64) {
    double vA = fmin(aA[tid], fmin(aA[tid + 64], aA[tid + 128]));
    double vB = fmin(aB[tid], fmin(aB[tid + 64], aB[tid + 128]));
#pragma unroll
    for (int o = 32; o > 0; o >>= 1) {
      vA = fmin(vA, __shfl_down(vA, o, 64));
      vB = fmin(vB, __shfl_down(vB, o, 64));
    }
    if (tid == 0) { red[10] = vA; red[11] = vB; }
  }
  __syncthreads();
  oA = red[10]; oB = red[11];
}

// per-s dot over d for TWO vectors vs one shared khT column (8 staged, 16 named accs)
#define SDOT2(vLA, vLB, khTp, outA, outB) do {                               \
    const float* cb_ = (khTp) + tid;                                         \
    double a0_=0,a1_=0,a2_=0,a3_=0,a4_=0,a5_=0,a6_=0,a7_=0;                  \
    double b0_=0,b1_=0,b2_=0,b3_=0,b4_=0,b5_=0,b6_=0,b7_=0;                  \
    for (int d0_ = 0; d0_ < DD; d0_ += 8) {                                  \
      float f0_ = cb_[(size_t)(d0_ + 0) * SS];                               \
      float f1_ = cb_[(size_t)(d0_ + 1) * SS];                               \
      float f2_ = cb_[(size_t)(d0_ + 2) * SS];                               \
      float f3_ = cb_[(size_t)(d0_ + 3) * SS];                               \
      float f4_ = cb_[(size_t)(d0_ + 4) * SS];                               \
      float f5_ = cb_[(size_t)(d0_ + 5) * SS];                               \
      float f6_ = cb_[(size_t)(d0_ + 6) * SS];                               \
      float f7_ = cb_[(size_t)(d0_ + 7) * SS];                               \
      a0_ += (vLA)[d0_ + 0] * (double)f0_;  b0_ += (vLB)[d0_ + 0] * (double)f0_; \
      a1_ += (vLA)[d0_ + 1] * (double)f1_;  b1_ += (vLB)[d0_ + 1] * (double)f1_; \
      a2_ += (vLA)[d0_ + 2] * (double)f2_;  b2_ += (vLB)[d0_ + 2] * (double)f2_; \
      a3_ += (vLA)[d0_ + 3] * (double)f3_;  b3_ += (vLB)[d0_ + 3] * (double)f3_; \
      a4_ += (vLA)[d0_ + 4] * (double)f4_;  b4_ += (vLB)[d0_ + 4] * (double)f4_; \
      a5_ += (vLA)[d0_ + 5] * (double)f5_;  b5_ += (vLB)[d0_ + 5] * (double)f5_; \
      a6_ += (vLA)[d0_ + 6] * (double)f6_;  b6_ += (vLB)[d0_ + 6] * (double)f6_; \
      a7_ += (vLA)[d0_ + 7] * (double)f7_;  b7_ += (vLB)[d0_ + 7] * (double)f7_; \
    }                                                                        \
    (outA) = ((a0_ + a1_) + (a2_ + a3_)) + ((a4_ + a5_) + (a6_ + a7_));      \
    (outB) = ((b0_ + b1_) + (b2_ + b3_)) + ((b4_ + b5_) + (b6_ + b7_));      \
  } while (0)

// d-mapped weighted sum over s for TWO weight arrays vs one shared matrix
#define DSUM2(wA, wB, mat, outA, outB) do {                                  \
    const float* mb_ = (mat);                                                \
    double a0_=0,a1_=0,a2_=0,a3_=0,a4_=0,a5_=0,a6_=0,a7_=0;                  \
    double b0_=0,b1_=0,b2_=0,b3_=0,b4_=0,b5_=0,b6_=0,b7_=0;                  \
    for (int t0_ = 0; t0_ < SS; t0_ += 8) {                                  \
      float f0_ = mb_[(size_t)(t0_ + 0) * DD];                               \
      float f1_ = mb_[(size_t)(t0_ + 1) * DD];                               \
      float f2_ = mb_[(size_t)(t0_ + 2) * DD];                               \
      float f3_ = mb_[(size_t)(t0_ + 3) * DD];                               \
      float f4_ = mb_[(size_t)(t0_ + 4) * DD];                               \
      float f5_ = mb_[(size_t)(t0_ + 5) * DD];                               \
      float f6_ = mb_[(size_t)(t0_ + 6) * DD];                               \
      float f7_ = mb_[(size_t)(t0_ + 7) * DD];                               \
      a0_ += (wA)[t0_ + 0] * (double)f0_;  b0_ += (wB)[t0_ + 0] * (double)f0_; \
      a1_ += (wA)[t0_ + 1] * (double)f1_;  b1_ += (wB)[t0_ + 1] * (double)f1_; \
      a2_ += (wA)[t0_ + 2] * (double)f2_;  b2_ += (wB)[t0_ + 2] * (double)f2_; \
      a3_ += (wA)[t0_ + 3] * (double)f3_;  b3_ += (wB)[t0_ + 3] * (double)f3_; \
      a4_ += (wA)[t0_ + 4] * (double)f4_;  b4_ += (wB)[t0_ + 4] * (double)f4_; \
      a5_ += (wA)[t0_ + 5] * (double)f5_;  b5_ += (wB)[t0_ + 5] * (double)f5_; \
      a6_ += (wA)[t0_ + 6] * (double)f6_;  b6_ += (wB)[t0_ + 6] * (double)f6_; \
      a7_ += (wA)[t0_ + 7] * (double)f7_;  b7_ += (wB)[t0_ + 7] * (double)f7_; \
    }                                                                        \
    (outA) = ((a0_ + a1_) + (a2_ + a3_)) + ((a4_ + a5_) + (a6_ + a7_));      \
    (outB) = ((b0_ + b1_) + (b2_ + b3_)) + ((b4_ + b5_) + (b6_ + b7_));      \
  } while (0)

// ---------------- W transpose ----------------
__global__ void transpose4(const float* __restrict__ Wq, const float* __restrict__ Wk,
                           const float* __restrict__ Wv, const float* __restrict__ Wo,
                           float* __restrict__ WqT, float* __restrict__ WkT,
                           float* __restrict__ WvT, float* __restrict__ WoT) {
  int m = blockIdx.x >> 8;
  int i = blockIdx.x & 255;
  int j = threadIdx.x;
  const float* S_; float* D_;
  if (m == 0) { S_ = Wq; D_ = WqT; }
  else if (m == 1) { S_ = Wk; D_ = WkT; }
  else if (m == 2) { S_ = Wv; D_ = WvT; }
  else { S_ = Wo; D_ = WoT; }
  D_[i * DD + j] = S_[j * DD + i];
}

// single-row blockSum (proj kernel only)
__device__ inline double blockSum(double v, double* red, int tid) {
#pragma unroll
  for (int o = 32; o > 0; o >>= 1) v += __shfl_down(v, o, 64);
  __syncthreads();
  if ((tid & 63) == 0) red[tid >> 6] = v;
  __syncthreads();
  return (red[0] + red[1]) + (red[2] + red[3]);
}

// dot of xs[LDS f32, len DD] with WT column j, 8 named f64 accumulators
__device__ inline double colDot(const float* __restrict__ xs,
                                const float* __restrict__ WT, int j) {
  const float* cb = WT + j;
  double s0=0.0,s1=0.0,s2=0.0,s3=0.0,s4=0.0,s5=0.0,s6=0.0,s7=0.0;
  for (int i0 = 0; i0 < DD; i0 += 8) {
    float f0 = cb[(size_t)(i0 + 0) * DD];
    float f1 = cb[(size_t)(i0 + 1) * DD];
    float f2 = cb[(size_t)(i0 + 2) * DD];
    float f3 = cb[(size_t)(i0 + 3) * DD];
    float f4 = cb[(size_t)(i0 + 4) * DD];
    float f5 = cb[(size_t)(i0 + 5) * DD];
    float f6 = cb[(size_t)(i0 + 6) * DD];
    float f7 = cb[(size_t)(i0 + 7) * DD];
    s0 += (double)xs[i0 + 0] * (double)f0;
    s1 += (double)xs[i0 + 1] * (double)f1;
    s2 += (double)xs[i0 + 2] * (double)f2;
    s3 += (double)xs[i0 + 3] * (double)f3;
    s4 += (double)xs[i0 + 4] * (double)f4;
    s5 += (double)xs[i0 + 5] * (double)f5;
    s6 += (double)xs[i0 + 6] * (double)f6;
    s7 += (double)xs[i0 + 7] * (double)f7;
  }
  return ((s0 + s1) + (s2 + s3)) + ((s4 + s5) + (s6 + s7));
}

// paired colDot: two LDS vectors vs one shared WT column
__device__ inline void colDot2(const float* __restrict__ xsA, const float* __restrict__ xsB,
                               const float* __restrict__ WT, int j,
                               double& oA, double& oB) {
  const float* cb = WT + j;
  double a0=0,a1=0,a2=0,a3=0, b0=0,b1=0,b2=0,b3=0;
  for (int i0 = 0; i0 < DD; i0 += 4) {
    float f0 = cb[(size_t)(i0 + 0) * DD];
    float f1 = cb[(size_t)(i0 + 1) * DD];
    float f2 = cb[(size_t)(i0 + 2) * DD];
    float f3 = cb[(size_t)(i0 + 3) * DD];
    a0 += (double)xsA[i0 + 0] * (double)f0;  b0 += (double)xsB[i0 + 0] * (double)f0;
    a1 += (double)xsA[i0 + 1] * (double)f1;  b1 += (double)xsB[i0 + 1] * (double)f1;
    a2 += (double)xsA[i0 + 2] * (double)f2;  b2 += (double)xsB[i0 + 2] * (double)f2;
    a3 += (double)xsA[i0 + 3] * (double)f3;  b3 += (double)xsB[i0 + 3] * (double)f3;
  }
  oA = (a0 + a1) + (a2 + a3);
  oB = (b0 + b1) + (b2 + b3);
}

// ---------------- fused QKV projection + expmap0 rows (round-4 exact) ----------------
__global__ __launch_bounds__(256) void proj_kernel(
    const float* __restrict__ q_in, const float* __restrict__ k_in, const float* __restrict__ v_in,
    const float* __restrict__ WqT, const float* __restrict__ WkT, const float* __restrict__ WvT,
    const float* __restrict__ bq, const float* __restrict__ bk, const float* __restrict__ bv,
    float* __restrict__ qh, float* __restrict__ kb, float* __restrict__ vb,
    float* __restrict__ kh, float* __restrict__ khT, double* __restrict__ y2g) {
  const int row = blockIdx.x, m = blockIdx.y, j = threadIdx.x;
  __shared__ float xs[DD];
  __shared__ double red[8];
  const float* x; const float* WT; const float* bias;
  if (m == 0) { x = q_in; WT = WqT; bias = bq; }
  else if (m == 1) { x = k_in; WT = WkT; bias = bk; }
  else { x = v_in; WT = WvT; bias = bv; }
  xs[j] = x[(size_t)row * DD + j];
  __syncthreads();
  double val = colDot(xs, WT, j) + (double)bias[j];

  if (m == 2) { vb[(size_t)row * DD + j] = (float)val; return; }

  double n2 = blockSum(val * val, red, j);
  double n = sqrt(n2);
  double cf = fmin(4.0 / (n + 1e-8), 1.0);
  double ncl = fmax(n * cf, 1e-15);
  double sc = tanh(ncl) * cf / ncl;
  if (m == 0) {
    qh[(size_t)row * DD + j] = (float)(val * sc);
  } else {
    kb[(size_t)row * DD + j] = (float)val;
    float khf = (float)(val * sc);
    kh[(size_t)row * DD + j] = khf;
    int bb = row / SS, s = row % SS;
    khT[((size_t)bb * DD + j) * SS + s] = khf;
    double y2 = blockSum((double)khf * (double)khf, red, j);
    if (j == 0) y2g[row] = y2;
  }
}

// ---------------- main fused kernel: 2 rows (same batch) per block ----------------
__global__ __launch_bounds__(256) void resonance_main(
    const float* __restrict__ q_hyp, const float* __restrict__ k_hyp,
    const float* __restrict__ k_hypT, const float* __restrict__ kmat,
    const float* __restrict__ vmat, const double* __restrict__ y2g,
    const float* __restrict__ WoT, const float* __restrict__ bo,
    const float* __restrict__ tau_p, const float* __restrict__ ts_p,
    float* __restrict__ out) {
  __shared__ double xqA[DD], xqB[DD], xcA[DD], xcB[DD], vrA[DD], vrB[DD];
  __shared__ double y2s[SS];
  __shared__ double wunA[SS], wunB[SS], wnsA[SS], wnsB[SS];
  __shared__ double alfA[SS], alfB[SS], betA[SS], betB[SS];
  __shared__ double sAA[SS], sAB[SS], sBA[SS], sBB[SS];
  __shared__ float hflA[DD], hflB[DD];
  __shared__ double red[16];
  const int tid = threadIdx.x;
  const int pblk = blockIdx.x;            // 0..191
  const int b = pblk / (SS / 2);
  const int qp = pblk % (SS / 2);
  const int rowA = b * SS + 2 * qp, rowB = rowA + 1;
  const size_t offA = (size_t)rowA * DD, offB = (size_t)rowB * DD;
  const float* khB = k_hyp + (size_t)b * SS * DD;
  const float* khT = k_hypT + (size_t)b * DD * SS;
  const float* kB = kmat + (size_t)b * SS * DD;
  const float* vB = vmat + (size_t)b * SS * DD;

  // inline JAX PRNG: nk = split(key(42), 3), partitionable scheme
  uint32_t nk0a, nk0b, nk1a, nk1b, nk2a, nk2b;
  threefry2x32(0u, 42u, 0u, 0u, &nk0a, &nk0b);
  threefry2x32(0u, 42u, 0u, 1u, &nk1a, &nk1b);
  threefry2x32(0u, 42u, 0u, 2u, &nk2a, &nk2b);
  const double noiseA = 1e-5 * (double)jax_normal_at(nk0a, nk0b, (uint32_t)(offA + tid));
  const double noiseB = 1e-5 * (double)jax_normal_at(nk0a, nk0b, (uint32_t)(offB + tid));
  const double vrndA = (double)jax_normal_at(nk1a, nk1b, (uint32_t)(offA + tid));
  const double vrndB = (double)jax_normal_at(nk1a, nk1b, (uint32_t)(offB + tid));
  const double odeA = 1e-4 * (double)jax_normal_at(nk2a, nk2b, (uint32_t)rowA);
  const double odeB = 1e-4 * (double)jax_normal_at(nk2a, nk2b, (uint32_t)rowB);

  double xqvA = (double)q_hyp[offA + tid];
  double xqvB = (double)q_hyp[offB + tid];
  xqA[tid] = xqvA;
  xqB[tid] = xqvB;
  if (tid < SS) y2s[tid] = y2g[b * SS + tid];
  double x2qA, x2qB;
  blockSum2(xqvA * xqvA, xqvB * xqvB, red, tid, x2qA, x2qB);  // syncs cover xq/y2s

  // ---- pairwise hyperbolic distance rows ----
  if (tid < SS) {
    double dA, dB;
    SDOT2(xqA, xqB, khT, dA, dB);
    double y2 = y2s[tid];
    {
      double A = 1.0 - 2.0 * dA + y2;
      double Dn = fmax(1.0 - 2.0 * dA + x2qA * y2, 1e-15);
      double Bc = 1.0 - x2qA;
      double u2 = (A * A * x2qA - 2.0 * A * Bc * dA + Bc * Bc * y2) / (Dn * Dn);
      double unr = sqrt(fmax(u2, 0.0));
      sAA[tid] = 2.0 * atanh(fmin(unr, 1.0 - 1e-7));
    }
    {
      double A = 1.0 - 2.0 * dB + y2;
      double Dn = fmax(1.0 - 2.0 * dB + x2qB * y2, 1e-15);
      double Bc = 1.0 - x2qB;
      double u2 = (A * A * x2qB - 2.0 * A * Bc * dB + Bc * Bc * y2) / (Dn * Dn);
      double unr = sqrt(fmax(u2, 0.0));
      sAB[tid] = 2.0 * atanh(fmin(unr, 1.0 - 1e-7));
    }
  }
  double mindA, mindB;
  reduceS_min2(sAA, sAB, red, tid, mindA, mindB);
  if (tid < SS) {
    wunA[tid] = exp(-(sAA[tid] - mindA));
    wunB[tid] = exp(-(sAB[tid] - mindB));
  }
  double wsA, wsB;
  reduceS_sum2(wunA, wunB, red, tid, wsA, wsB);
  if (tid < SS) {
    wnsA[tid] = wunA[tid] * (1.0 / (wsA + 1e-8));
    wnsB[tid] = wunB[tid] * (1.0 / (wsB + 1e-8));
  }
  __syncthreads();

  // ---- fused: h = wns.v, mu = wns.k for both rows (shared v/k loads) ----
  double hregA, hregB, muA, muB;
  {
    const float* vb_ = vB + tid;
    const float* kb_ = kB + tid;
    double hA0=0,hA1=0,hB0=0,hB1=0, mA0=0,mA1=0,mB0=0,mB1=0;
    for (int s0 = 0; s0 < SS; s0 += 4) {
      float v0 = vb_[(size_t)(s0 + 0) * DD];
      float v1 = vb_[(size_t)(s0 + 1) * DD];
      float v2 = vb_[(size_t)(s0 + 2) * DD];
      float v3 = vb_[(size_t)(s0 + 3) * DD];
      float k0 = kb_[(size_t)(s0 + 0) * DD];
      float k1 = kb_[(size_t)(s0 + 1) * DD];
      float k2 = kb_[(size_t)(s0 + 2) * DD];
      float k3 = kb_[(size_t)(s0 + 3) * DD];
      double wA0 = wnsA[s0 + 0], wA1 = wnsA[s0 + 1], wA2 = wnsA[s0 + 2], wA3 = wnsA[s0 + 3];
      double wB0 = wnsB[s0 + 0], wB1 = wnsB[s0 + 1], wB2 = wnsB[s0 + 2], wB3 = wnsB[s0 + 3];
      hA0 += wA0 * (double)v0; hB0 += wB0 * (double)v0;
      mA0 += wA0 * (double)k0; mB0 += wB0 * (double)k0;
      hA1 += wA1 * (double)v1; hB1 += wB1 * (double)v1;
      mA1 += wA1 * (double)k1; mB1 += wB1 * (double)k1;
      hA0 += wA2 * (double)v2; hB0 += wB2 * (double)v2;
      mA0 += wA2 * (double)k2; mB0 += wB2 * (double)k2;
      hA1 += wA3 * (double)v3; hB1 += wB3 * (double)v3;
      mA1 += wA3 * (double)k3; mB1 += wB3 * (double)k3;
    }
    hregA = hA0 + hA1; hregB = hB0 + hB1;
    muA = mA0 + mA1;   muB = mB0 + mB1;
  }

  // ---- mu0 = expmap0(clip_tangent(mu)) ----
  double x2cA, x2cB;
  {
    double n2A, n2B;
    blockSum2(muA * muA, muB * muB, red, tid, n2A, n2B);
    {
      double n = sqrt(n2A);
      double cf = fmin(4.0 / (n + 1e-8), 1.0);
      double ncl = fmax(n * cf, 1e-15);
      double th = tanh(ncl);
      xcA[tid] = muA * (th * cf / ncl);
      x2cA = th * th;
    }
    {
      double n = sqrt(n2B);
      double cf = fmin(4.0 / (n + 1e-8), 1.0);
      double ncl = fmax(n * cf, 1e-15);
      double th = tanh(ncl);
      xcB[tid] = muB * (th * cf / ncl);
      x2cB = th * th;
    }
  }
  __syncthreads();

  // ---- Karcher flow: 3 Riemannian SGD steps ----
  for (int it = 0; it < 3; ++it) {
    if (tid < SS) {
      double dA, dB;
      SDOT2(xcA, xcB, khT, dA, dB);
      double y2 = y2s[tid];
      {
        double A = 1.0 - 2.0 * dA + y2;
        double Dn = fmax(1.0 - 2.0 * dA + x2cA * y2, 1e-15);
        double Bc = 1.0 - x2cA;
        double u2 = (A * A * x2cA - 2.0 * A * Bc * dA + Bc * Bc * y2) / (Dn * Dn);
        double unr = sqrt(fmax(u2, 0.0));
        double un = fmax(unr, 1e-15);
        double coef = fmax(Bc, 1e-15) * atanh(fmin(un, 1.0 - 1e-7)) / un;
        double cs = wnsA[tid] * coef / Dn;
        sAA[tid] = cs;
        sBA[tid] = cs * A;
      }
      {
        double A = 1.0 - 2.0 * dB + y2;
        double Dn = fmax(1.0 - 2.0 * dB + x2cB * y2, 1e-15);
        double Bc = 1.0 - x2cB;
        double u2 = (A * A * x2cB - 2.0 * A * Bc * dB + Bc * Bc * y2) / (Dn * Dn);
        double unr = sqrt(fmax(u2, 0.0));
        double un = fmax(unr, 1e-15);
        double coef = fmax(Bc, 1e-15) * atanh(fmin(un, 1.0 - 1e-7)) / un;
        double cs = wnsB[tid] * coef / Dn;
        sAB[tid] = cs;
        sBB[tid] = cs * A;
      }
    }
    double S1A, S1B;
    reduceS_sum2(sBA, sBB, red, tid, S1A, S1B);   // syncs cover sA/sB writes
    double gA, gB;
    DSUM2(sAA, sAB, khB + tid, gA, gB);
    double xoldA = xcA[tid], xoldB = xcB[tid];
    double BcA = 1.0 - x2cA, BcB = 1.0 - x2cB;
    double vgA = BcA * gA - S1A * xoldA;
    double vgB = BcB * gB - S1B * xoldB;
    double nv2A, nv2B;
    blockSum2(vgA * vgA, vgB * vgB, red, tid, nv2A, nv2B);
    double zA, z2A, zB, z2B;
    {
      double nv = 0.1 * sqrt(nv2A);
      double cf = fmin(4.0 / (nv + 1e-8), 1.0);
      double nw = fmax(nv * cf, 1e-15);
      double tsc = tanh(nw / fmax(BcA, 1e-15));
      zA = tsc * 0.1 * cf / nw * vgA;
      z2A = tsc * tsc;
    }
    {
      double nv = 0.1 * sqrt(nv2B);
      double cf = fmin(4.0 / (nv + 1e-8), 1.0);
      double nw = fmax(nv * cf, 1e-15);
      double tsc = tanh(nw / fmax(BcB, 1e-15));
      zB = tsc * 0.1 * cf / nw * vgB;
      z2B = tsc * tsc;
    }
    double xzA, xzB;
    blockSum2(xoldA * zA, xoldB * zB, red, tid, xzA, xzB);
    double xnewA = ((1.0 + 2.0 * xzA + z2A) * xoldA + (1.0 - x2cA) * zA) /
                   fmax(1.0 + 2.0 * xzA + x2cA * z2A, 1e-15);
    double xnewB = ((1.0 + 2.0 * xzB + z2B) * xoldB + (1.0 - x2cB) * zB) /
                   fmax(1.0 + 2.0 * xzB + x2cB * z2B, 1e-15);
    xcA[tid] = xnewA;
    xcB[tid] = xnewB;
    blockSum2(xnewA * xnewA, xnewB * xnewB, red, tid, x2cA, x2cB);  // syncs cover xc
  }

  // ---- k_centroid = projx(mu + noise) ----
  {
    double cnA = xcA[tid] + noiseA;
    double cnB = xcB[tid] + noiseB;
    double n2A, n2B;
    blockSum2(cnA * cnA, cnB * cnB, red, tid, n2A, n2B);
    double nnA = sqrt(n2A), nnB = sqrt(n2B);
    if (nnA > 1.0 - 1e-5) cnA *= (1.0 - 1e-5) / fmax(nnA, 1e-15);
    if (nnB > 1.0 - 1e-5) cnB *= (1.0 - 1e-5) / fmax(nnB, 1e-15);
    xcA[tid] = cnA;
    xcB[tid] = cnB;
    blockSum2(cnA * cnA, cnB * cnB, red, tid, x2cA, x2cB);          // syncs cover xc
  }

  // ---- c2k distances, entropy, variance; alf/bet ----
  if (tid < SS) {
    double dA, dB;
    SDOT2(xcA, xcB, khT, dA, dB);
    double y2 = y2s[tid];
    {
      double A = 1.0 - 2.0 * dA + y2;
      double Dn = fmax(1.0 - 2.0 * dA + x2cA * y2, 1e-15);
      double Bc = 1.0 - x2cA;
      double u2 = (A * A * x2cA - 2.0 * A * Bc * dA + Bc * Bc * y2) / (Dn * Dn);
      double unr = sqrt(fmax(u2, 0.0));
      double c2k = 2.0 * atanh(fmin(unr, 1.0 - 1e-7));
      sAA[tid] = wnsA[tid] * c2k * c2k;
      sBA[tid] = -wnsA[tid] * log(wnsA[tid] + 1e-8);
      double un = fmax(unr, 1e-15);
      double gl = fmax(Bc, 1e-15) * atanh(fmin(un, 1.0 - 1e-7)) / (un * Dn);
      double sq = sqrt(wunA[tid] + 1e-8);
      alfA[tid] = -sq * gl * A;
      betA[tid] = sq * gl * Bc;
    }
    {
      double A = 1.0 - 2.0 * dB + y2;
      double Dn = fmax(1.0 - 2.0 * dB + x2cB * y2, 1e-15);
      double Bc = 1.0 - x2cB;
      double u2 = (A * A * x2cB - 2.0 * A * Bc * dB + Bc * Bc * y2) / (Dn * Dn);
      double unr = sqrt(fmax(u2, 0.0));
      double c2k = 2.0 * atanh(fmin(unr, 1.0 - 1e-7));
      sAB[tid] = wnsB[tid] * c2k * c2k;
      sBB[tid] = -wnsB[tid] * log(wnsB[tid] + 1e-8);
      double un = fmax(unr, 1e-15);
      double gl = fmax(Bc, 1e-15) * atanh(fmin(un, 1.0 - 1e-7)) / (un * Dn);
      double sq = sqrt(wunB[tid] + 1e-8);
      alfB[tid] = -sq * gl * A;
      betB[tid] = sq * gl * Bc;
    }
  }
  double varA, varB, entA, entB;
  reduceS_sum2(sAA, sAB, red, tid, varA, varB);
  reduceS_sum2(sBA, sBB, red, tid, entA, entB);
  double tau = (double)tau_p[0];
  double tensionA = varA - tau * exp(entA);
  double tensionB = varB - tau * exp(entB);

  // ---- power iteration ----
  {
    double n2A, n2B;
    blockSum2(vrndA * vrndA, vrndB * vrndB, red, tid, n2A, n2B);
    vrA[tid] = vrndA / fmax(sqrt(n2A), 1e-8);
    vrB[tid] = vrndB / fmax(sqrt(n2B), 1e-8);
  }
  for (int it = 0; it < 3; ++it) {
    double dxvA, dxvB;
    blockSum2(xcA[tid] * vrA[tid], xcB[tid] * vrB[tid], red, tid, dxvA, dxvB);
    if (tid < SS) {
      double dA, dB;
      SDOT2(vrA, vrB, khT, dA, dB);
      double pjA = alfA[tid] * dxvA + betA[tid] * dA;
      double pjB = alfB[tid] * dxvB + betB[tid] * dB;
      sAA[tid] = alfA[tid] * pjA;
      sBA[tid] = betA[tid] * pjA;
      sAB[tid] = alfB[tid] * pjB;
      sBB[tid] = betB[tid] * pjB;
    }
    double T1A, T1B;
    reduceS_sum2(sAA, sAB, red, tid, T1A, T1B);
    double gA, gB;
    DSUM2(sBA, sBB, khB + tid, gA, gB);
    double vnewA = T1A * xcA[tid] + gA;
    double vnewB = T1B * xcB[tid] + gB;
    double n2A, n2B;
    blockSum2(vnewA * vnewA, vnewB * vnewB, red, tid, n2A, n2B);
    vrA[tid] = vnewA / fmax(sqrt(n2A), 1e-8);
    vrB[tid] = vnewB / fmax(sqrt(n2B), 1e-8);
  }

  // ---- w_proj ----
  double wprojA, wprojB;
  {
    double fA, fB;
    {
      double nq = fmax(sqrt(x2qA), 1e-15);
      double aq = atanh(fmin(nq, 1.0 - 1e-7)) / nq;
      double nc = fmax(sqrt(x2cA), 1e-15);
      double ac = atanh(fmin(nc, 1.0 - 1e-7)) / nc;
      fA = aq * xqA[tid] - ac * xcA[tid];
    }
    {
      double nq = fmax(sqrt(x2qB), 1e-15);
      double aq = atanh(fmin(nq, 1.0 - 1e-7)) / nq;
      double nc = fmax(sqrt(x2cB), 1e-15);
      double ac = atanh(fmin(nc, 1.0 - 1e-7)) / nc;
      fB = aq * xqB[tid] - ac * xcB[tid];
    }
    double n2A, n2B;
    blockSum2(fA * fA, fB * fB, red, tid, n2A, n2B);
    double wgA = vrA[tid] / fmax(1.0 - x2cA, 1e-15);
    double wgB = vrB[tid] / fmax(1.0 - x2cB, 1e-15);
    wprojA = (varA > 1e-5) ? wgA : (fA / fmax(sqrt(n2A), 1e-8));
    wprojB = (varB > 1e-5) ? wgB : (fB / fmax(sqrt(n2B), 1e-8));
  }

  // ---- h_comp, x, pitchfork RK4 ----
  double hn2A, hn2B;
  blockSum2(hregA * hregA, hregB * hregB, red, tid, hn2A, hn2B);
  double hnA = sqrt(hn2A), hnB = sqrt(hn2B);
  double hcA = asinh(hnA) / (hnA + 1e-8) * hregA;
  double hcB = asinh(hnB) / (hnB + 1e-8) * hregB;
  double xA, xB;
  blockSum2(hcA * wprojA, hcB * wprojB, red, tid, xA, xB);
  double xiA = (xA == 0.0) ? odeA : xA;
  double xiB = (xB == 0.0) ? odeB : xB;
  const double dt = 0.5;
#pragma unroll
  for (int r = 0; r < 4; ++r) {
    {
      double k1 = dt * (tensionA * xiA - xiA * xiA * xiA);
      double a2 = xiA + 0.5 * k1;
      double k2 = dt * (tensionA * a2 - a2 * a2 * a2);
      double a3 = xiA + 0.5 * k2;
      double k3 = dt * (tensionA * a3 - a3 * a3 * a3);
      double a4 = xiA + k3;
      double k4 = dt * (tensionA * a4 - a4 * a4 * a4);
      xiA += (k1 + 2.0 * k2 + 2.0 * k3 + k4) / 6.0;
    }
    {
      double k1 = dt * (tensionB * xiB - xiB * xiB * xiB);
      double a2 = xiB + 0.5 * k1;
      double k2 = dt * (tensionB * a2 - a2 * a2 * a2);
      double a3 = xiB + 0.5 * k2;
      double k3 = dt * (tensionB * a3 - a3 * a3 * a3);
      double a4 = xiB + k3;
      double k4 = dt * (tensionB * a4 - a4 * a4 * a4);
      xiB += (k1 + 2.0 * k2 + 2.0 * k3 + k4) / 6.0;
    }
  }
  double ts = (double)ts_p[0];
  double hpA = (hcA + (xiA - xA) * wprojA) * ts;
  double hpB = (hcB + (xiB - xB) * wprojB) * ts;
  double hp2A, hp2B;
  blockSum2(hpA * hpA, hpB * hpB, red, tid, hp2A, hp2B);
  double hobA, hobB;
  {
    double nhp = sqrt(hp2A);
    double cf = fmin(4.0 / (nhp + 1e-8), 1.0);
    double ncl = fmax(nhp * cf, 1e-15);
    double th = tanh(ncl);
    double nb = fmax(th, 1e-15);
    double ab = atanh(fmin(nb, 1.0 - 1e-7)) / nb;
    hobA = ab * th * cf / ncl * hpA;
  }
  {
    double nhp = sqrt(hp2B);
    double cf = fmin(4.0 / (nhp + 1e-8), 1.0);
    double ncl = fmax(nhp * cf, 1e-15);
    double th = tanh(ncl);
    double nb = fmax(th, 1e-15);
    double ab = atanh(fmin(nb, 1.0 - 1e-7)) / nb;
    hobB = ab * th * cf / ncl * hpB;
  }
  double gateA = fmax(tanh(tensionA / fmax(tau, 1e-3)), 0.0);
  double gateB = fmax(tanh(tensionB / fmax(tau, 1e-3)), 0.0);

  // ---- fused output GEMM for both rows (shared WoT column loads) ----
  hflA[tid] = (float)((1.0 - gateA) * hregA + gateA * hobA);
  hflB[tid] = (float)((1.0 - gateB) * hregB + gateB * hobB);
  __syncthreads();
  double oA, oB;
  colDot2(hflA, hflB, WoT, tid, oA, oB);
  double bias = (double)bo[tid];
  out[offA + tid] = (float)(oA + bias);
  out[offB + tid] = (float)(oB + bias);
}

// ---------------- launch ----------------
extern "C" void kernel_launch(void* const* d_in, const int* in_sizes, int n_in,
                              void* d_out, int out_size, void* d_ws, size_t ws_size,
                              hipStream_t stream) {
  const float* q_in = (const float*)d_in[0];
  const float* k_in = (const float*)d_in[1];
  const float* v_in = (const float*)d_in[2];
  const float* Wq = (const float*)d_in[3];
  const float* bq = (const float*)d_in[4];
  const float* Wk = (const float*)d_in[5];
  const float* bk = (const float*)d_in[6];
  const float* Wv = (const float*)d_in[7];
  const float* bv = (const float*)d_in[8];
  const float* Wo = (const float*)d_in[9];
  const float* bo = (const float*)d_in[10];
  const float* tau = (const float*)d_in[11];
  const float* ts = (const float*)d_in[12];
  float* out = (float*)d_out;
  (void)in_sizes; (void)n_in; (void)out_size; (void)ws_size;

  char* base = (char*)d_ws;
  size_t off = 0;
  auto alloc = [&](size_t bytes) -> void* {
    void* p = base + off;
    off += (bytes + 255) & ~(size_t)255;
    return p;
  };
  float* WqT = (float*)alloc((size_t)DD * DD * 4);
  float* WkT = (float*)alloc((size_t)DD * DD * 4);
  float* WvT = (float*)alloc((size_t)DD * DD * 4);
  float* WoT = (float*)alloc((size_t)DD * DD * 4);
  float* kb = (float*)alloc((size_t)NE * 4);
  float* vb = (float*)alloc((size_t)NE * 4);
  float* qh = (float*)alloc((size_t)NE * 4);
  float* kh = (float*)alloc((size_t)NE * 4);
  float* khT = (float*)alloc((size_t)NE * 4);
  double* y2g = (double*)alloc((size_t)NROW * 8);

  hipLaunchKernelGGL(transpose4, dim3(4 * DD), dim3(DD), 0, stream,
                     Wq, Wk, Wv, Wo, WqT, WkT, WvT, WoT);
  hipLaunchKernelGGL(proj_kernel, dim3(NROW, 3), dim3(DD), 0, stream,
                     q_in, k_in, v_in, WqT, WkT, WvT, bq, bk, bv,
                     qh, kb, vb, kh, khT, y2g);
  hipLaunchKernelGGL(resonance_main, dim3(NROW / 2), dim3(DD), 0, stream,
                     qh, kh, khT, kb, vb, y2g, WoT, bo, tau, ts, out);
}

// Round 11
// 146.019 us; speedup vs baseline: 1.1431x; 1.1431x over previous
//
#include <hip/hip_runtime.h>
#include <hip/hip_bf16.h>
#include <stdint.h>

#define BB 2
#define SS 192
#define DD 256
#define NROW (BB * SS)   // 384
#define NE (NROW * DD)   // 98304

// ---------------- threefry2x32-20 (Random123 / JAX, partitionable) ----------------
__device__ __forceinline__ uint32_t rotl32(uint32_t v, int d) {
  return (v << d) | (v >> (32 - d));
}

__device__ inline void threefry2x32(uint32_t k0, uint32_t k1, uint32_t x0, uint32_t x1,
                                    uint32_t* o0, uint32_t* o1) {
  uint32_t ks2 = k0 ^ k1 ^ 0x1BD11BDAu;
  x0 += k0; x1 += k1;
  const int ra[4] = {13, 15, 26, 6};
  const int rb[4] = {17, 29, 16, 24};
#pragma unroll
  for (int i = 0; i < 4; i++) { x0 += x1; x1 = rotl32(x1, ra[i]); x1 ^= x0; }
  x0 += k1; x1 += ks2 + 1u;
#pragma unroll
  for (int i = 0; i < 4; i++) { x0 += x1; x1 = rotl32(x1, rb[i]); x1 ^= x0; }
  x0 += ks2; x1 += k0 + 2u;
#pragma unroll
  for (int i = 0; i < 4; i++) { x0 += x1; x1 = rotl32(x1, ra[i]); x1 ^= x0; }
  x0 += k0; x1 += k1 + 3u;
#pragma unroll
  for (int i = 0; i < 4; i++) { x0 += x1; x1 = rotl32(x1, rb[i]); x1 ^= x0; }
  x0 += k1; x1 += ks2 + 4u;
#pragma unroll
  for (int i = 0; i < 4; i++) { x0 += x1; x1 = rotl32(x1, ra[i]); x1 ^= x0; }
  x0 += ks2; x1 += k0 + 5u;
  *o0 = x0; *o1 = x1;
}

__device__ inline float erfinv_xla_f32(float x) {
  float w = -log1pf(-x * x);
  float p;
  if (w < 5.0f) {
    w = w - 2.5f;
    p = 2.81022636e-08f;
    p = 3.43273939e-07f + p * w;
    p = -3.5233877e-06f + p * w;
    p = -4.39150654e-06f + p * w;
    p = 0.00021858087f + p * w;
    p = -0.00125372503f + p * w;
    p = -0.00417768164f + p * w;
    p = 0.246640727f + p * w;
    p = 1.50140941f + p * w;
  } else {
    w = sqrtf(w) - 3.0f;
    p = -0.000200214257f;
    p = 0.000100950558f + p * w;
    p = 0.00134934322f + p * w;
    p = -0.00367342844f + p * w;
    p = 0.00573950773f + p * w;
    p = -0.0076224613f + p * w;
    p = 0.00943887047f + p * w;
    p = 1.00167406f + p * w;
    p = 2.83297682f + p * w;
  }
  return p * x;
}

__device__ inline float jax_normal_from_bits(uint32_t bits) {
  float f = __uint_as_float((bits >> 9) | 0x3f800000u) - 1.0f;
  const float lo = -0.99999994f;  // nextafter(-1, 0)
  float u = f * (1.0f - lo) + lo;
  u = fmaxf(lo, u);
  return 1.4142135623730951f * erfinv_xla_f32(u);
}

__device__ inline float jax_normal_at(uint32_t ka, uint32_t kb, uint32_t i) {
  uint32_t o0, o1;
  threefry2x32(ka, kb, 0u, i, &o0, &o1);
  return jax_normal_from_bits(o0 ^ o1);
}

// ---------------- reductions (256 threads = 4 waves of 64) ----------------
__device__ inline double blockSum(double v, double* red, int tid) {
#pragma unroll
  for (int o = 32; o > 0; o >>= 1) v += __shfl_down(v, o, 64);
  __syncthreads();
  if ((tid & 63) == 0) red[tid >> 6] = v;
  __syncthreads();
  return (red[0] + red[1]) + (red[2] + red[3]);
}

__device__ inline void blockSum2(double vA, double vB, double* red, int tid,
                                 double& oA, double& oB) {
#pragma unroll
  for (int o = 32; o > 0; o >>= 1) {
    vA += __shfl_down(vA, o, 64);
    vB += __shfl_down(vB, o, 64);
  }
  __syncthreads();
  if ((tid & 63) == 0) { red[tid >> 6] = vA; red[4 + (tid >> 6)] = vB; }
  __syncthreads();
  oA = (red[0] + red[1]) + (red[2] + red[3]);
  oB = (red[4] + red[5]) + (red[6] + red[7]);
}

__device__ inline double reduceS_sum(const double* arr, double* red, int tid) {
  __syncthreads();
  if (tid < 64) {
    double v = arr[tid] + arr[tid + 64] + arr[tid + 128];
#pragma unroll
    for (int o = 32; o > 0; o >>= 1) v += __shfl_down(v, o, 64);
    if (tid == 0) red[8] = v;
  }
  __syncthreads();
  return red[8];
}

__device__ inline void reduceS_sum2(const double* aA, const double* aB, double* red,
                                    int tid, double& oA, double& oB) {
  __syncthreads();
  if (tid < 64) {
    double vA = aA[tid] + aA[tid + 64] + aA[tid + 128];
    double vB = aB[tid] + aB[tid + 64] + aB[tid + 128];
#pragma unroll
    for (int o = 32; o > 0; o >>= 1) {
      vA += __shfl_down(vA, o, 64);
      vB += __shfl_down(vB, o, 64);
    }
    if (tid == 0) { red[8] = vA; red[9] = vB; }
  }
  __syncthreads();
  oA = red[8]; oB = red[9];
}

__device__ inline double reduceS_min(const double* arr, double* red, int tid) {
  __syncthreads();
  if (tid < 64) {
    double v = fmin(arr[tid], fmin(arr[tid + 64], arr[tid + 128]));
#pragma unroll
    for (int o = 32; o > 0; o >>= 1) v = fmin(v, __shfl_down(v, o, 64));
    if (tid == 0) red[10] = v;
  }
  __syncthreads();
  return red[10];
}

// per-s dot over d (tid < SS): 8 NAMED f64 accumulators, loads staged in named floats
#define SDOT(vecLds, khTp, outv) do {                                        \
    const float* cb_ = (khTp) + tid;                                         \
    double s0_=0.0,s1_=0.0,s2_=0.0,s3_=0.0,s4_=0.0,s5_=0.0,s6_=0.0,s7_=0.0;  \
    for (int d0_ = 0; d0_ < DD; d0_ += 8) {                                  \
      float f0_ = cb_[(size_t)(d0_ + 0) * SS];                               \
      float f1_ = cb_[(size_t)(d0_ + 1) * SS];                               \
      float f2_ = cb_[(size_t)(d0_ + 2) * SS];                               \
      float f3_ = cb_[(size_t)(d0_ + 3) * SS];                               \
      float f4_ = cb_[(size_t)(d0_ + 4) * SS];                               \
      float f5_ = cb_[(size_t)(d0_ + 5) * SS];                               \
      float f6_ = cb_[(size_t)(d0_ + 6) * SS];                               \
      float f7_ = cb_[(size_t)(d0_ + 7) * SS];                               \
      s0_ += (vecLds)[d0_ + 0] * (double)f0_;                                \
      s1_ += (vecLds)[d0_ + 1] * (double)f1_;                                \
      s2_ += (vecLds)[d0_ + 2] * (double)f2_;                                \
      s3_ += (vecLds)[d0_ + 3] * (double)f3_;                                \
      s4_ += (vecLds)[d0_ + 4] * (double)f4_;                                \
      s5_ += (vecLds)[d0_ + 5] * (double)f5_;                                \
      s6_ += (vecLds)[d0_ + 6] * (double)f6_;                                \
      s7_ += (vecLds)[d0_ + 7] * (double)f7_;                                \
    }                                                                        \
    (outv) = ((s0_ + s1_) + (s2_ + s3_)) + ((s4_ + s5_) + (s6_ + s7_));      \
  } while (0)

// d-mapped weighted sum over s: sum_s wArr[s] * mat[s*DD + tid]
#define DSUM(wArr, mat, outv) do {                                           \
    const float* mb_ = (mat) + tid;                                          \
    double s0_=0.0,s1_=0.0,s2_=0.0,s3_=0.0,s4_=0.0,s5_=0.0,s6_=0.0,s7_=0.0;  \
    for (int t0_ = 0; t0_ < SS; t0_ += 8) {                                  \
      float f0_ = mb_[(size_t)(t0_ + 0) * DD];                               \
      float f1_ = mb_[(size_t)(t0_ + 1) * DD];                               \
      float f2_ = mb_[(size_t)(t0_ + 2) * DD];                               \
      float f3_ = mb_[(size_t)(t0_ + 3) * DD];                               \
      float f4_ = mb_[(size_t)(t0_ + 4) * DD];                               \
      float f5_ = mb_[(size_t)(t0_ + 5) * DD];                               \
      float f6_ = mb_[(size_t)(t0_ + 6) * DD];                               \
      float f7_ = mb_[(size_t)(t0_ + 7) * DD];                               \
      s0_ += (wArr)[t0_ + 0] * (double)f0_;                                  \
      s1_ += (wArr)[t0_ + 1] * (double)f1_;                                  \
      s2_ += (wArr)[t0_ + 2] * (double)f2_;                                  \
      s3_ += (wArr)[t0_ + 3] * (double)f3_;                                  \
      s4_ += (wArr)[t0_ + 4] * (double)f4_;                                  \
      s5_ += (wArr)[t0_ + 5] * (double)f5_;                                  \
      s6_ += (wArr)[t0_ + 6] * (double)f6_;                                  \
      s7_ += (wArr)[t0_ + 7] * (double)f7_;                                  \
    }                                                                        \
    (outv) = ((s0_ + s1_) + (s2_ + s3_)) + ((s4_ + s5_) + (s6_ + s7_));      \
  } while (0)

// ---------------- W transpose ----------------
__global__ void transpose4(const float* __restrict__ Wq, const float* __restrict__ Wk,
                           const float* __restrict__ Wv, const float* __restrict__ Wo,
                           float* __restrict__ WqT, float* __restrict__ WkT,
                           float* __restrict__ WvT, float* __restrict__ WoT) {
  int m = blockIdx.x >> 8;
  int i = blockIdx.x & 255;
  int j = threadIdx.x;
  const float* S_; float* D_;
  if (m == 0) { S_ = Wq; D_ = WqT; }
  else if (m == 1) { S_ = Wk; D_ = WkT; }
  else if (m == 2) { S_ = Wv; D_ = WvT; }
  else { S_ = Wo; D_ = WoT; }
  D_[i * DD + j] = S_[j * DD + i];
}

// dot of xs[LDS f32, len DD] with WT column j, 8 named f64 accumulators
__device__ inline double colDot(const float* __restrict__ xs,
                                const float* __restrict__ WT, int j) {
  const float* cb = WT + j;
  double s0=0.0,s1=0.0,s2=0.0,s3=0.0,s4=0.0,s5=0.0,s6=0.0,s7=0.0;
  for (int i0 = 0; i0 < DD; i0 += 8) {
    float f0 = cb[(size_t)(i0 + 0) * DD];
    float f1 = cb[(size_t)(i0 + 1) * DD];
    float f2 = cb[(size_t)(i0 + 2) * DD];
    float f3 = cb[(size_t)(i0 + 3) * DD];
    float f4 = cb[(size_t)(i0 + 4) * DD];
    float f5 = cb[(size_t)(i0 + 5) * DD];
    float f6 = cb[(size_t)(i0 + 6) * DD];
    float f7 = cb[(size_t)(i0 + 7) * DD];
    s0 += (double)xs[i0 + 0] * (double)f0;
    s1 += (double)xs[i0 + 1] * (double)f1;
    s2 += (double)xs[i0 + 2] * (double)f2;
    s3 += (double)xs[i0 + 3] * (double)f3;
    s4 += (double)xs[i0 + 4] * (double)f4;
    s5 += (double)xs[i0 + 5] * (double)f5;
    s6 += (double)xs[i0 + 6] * (double)f6;
    s7 += (double)xs[i0 + 7] * (double)f7;
  }
  return ((s0 + s1) + (s2 + s3)) + ((s4 + s5) + (s6 + s7));
}

// ---------------- fused QKV projection + expmap0 rows (round-4 exact) ----------------
__global__ __launch_bounds__(256) void proj_kernel(
    const float* __restrict__ q_in, const float* __restrict__ k_in, const float* __restrict__ v_in,
    const float* __restrict__ WqT, const float* __restrict__ WkT, const float* __restrict__ WvT,
    const float* __restrict__ bq, const float* __restrict__ bk, const float* __restrict__ bv,
    float* __restrict__ qh, float* __restrict__ kb, float* __restrict__ vb,
    float* __restrict__ kh, float* __restrict__ khT, double* __restrict__ y2g) {
  const int row = blockIdx.x, m = blockIdx.y, j = threadIdx.x;
  __shared__ float xs[DD];
  __shared__ double red[12];
  const float* x; const float* WT; const float* bias;
  if (m == 0) { x = q_in; WT = WqT; bias = bq; }
  else if (m == 1) { x = k_in; WT = WkT; bias = bk; }
  else { x = v_in; WT = WvT; bias = bv; }
  xs[j] = x[(size_t)row * DD + j];
  __syncthreads();
  double val = colDot(xs, WT, j) + (double)bias[j];

  if (m == 2) { vb[(size_t)row * DD + j] = (float)val; return; }

  double n2 = blockSum(val * val, red, j);
  double n = sqrt(n2);
  double cf = fmin(4.0 / (n + 1e-8), 1.0);
  double ncl = fmax(n * cf, 1e-15);
  double sc = tanh(ncl) * cf / ncl;
  if (m == 0) {
    qh[(size_t)row * DD + j] = (float)(val * sc);
  } else {
    kb[(size_t)row * DD + j] = (float)val;
    float khf = (float)(val * sc);
    kh[(size_t)row * DD + j] = khf;
    int bb = row / SS, s = row % SS;
    khT[((size_t)bb * DD + j) * SS + s] = khf;
    double y2 = blockSum((double)khf * (double)khf, red, j);
    if (j == 0) y2g[row] = y2;
  }
}

// ---------------- main fused per-(b,q) kernel (r9 + hmu8+8 + fewer reductions) ----------------
__global__ __launch_bounds__(256) void resonance_main(
    const float* __restrict__ q_hyp, const float* __restrict__ k_hyp,
    const float* __restrict__ k_hypT, const float* __restrict__ kmat,
    const float* __restrict__ vmat, const double* __restrict__ y2g,
    const float* __restrict__ WoT, const float* __restrict__ bo,
    const float* __restrict__ tau_p, const float* __restrict__ ts_p,
    float* __restrict__ out) {
  __shared__ double xq[DD], xc[DD], vr[DD];
  __shared__ double y2s[SS], wun[SS], wns[SS], alf[SS], bet[SS], sA[SS], sB[SS];
  __shared__ float hfl[DD];
  __shared__ double red[12];
  const int tid = threadIdx.x;
  const int blk = blockIdx.x;
  const int b = blk / SS;
  const size_t rowOff = (size_t)blk * DD;
  const float* khB = k_hyp + (size_t)b * SS * DD;
  const float* khT = k_hypT + (size_t)b * DD * SS;
  const float* kB = kmat + (size_t)b * SS * DD;
  const float* vB = vmat + (size_t)b * SS * DD;

  // inline JAX PRNG: nk = split(key(42), 3), partitionable scheme
  uint32_t nk0a, nk0b, nk1a, nk1b, nk2a, nk2b;
  threefry2x32(0u, 42u, 0u, 0u, &nk0a, &nk0b);
  threefry2x32(0u, 42u, 0u, 1u, &nk1a, &nk1b);
  threefry2x32(0u, 42u, 0u, 2u, &nk2a, &nk2b);
  const uint32_t ei = (uint32_t)(rowOff + tid);
  const double noiseval = 1e-5 * (double)jax_normal_at(nk0a, nk0b, ei);
  const double vrndval = (double)jax_normal_at(nk1a, nk1b, ei);
  const double odeval = 1e-4 * (double)jax_normal_at(nk2a, nk2b, (uint32_t)blk);

  double xqv = (double)q_hyp[rowOff + tid];
  xq[tid] = xqv;
  if (tid < SS) y2s[tid] = y2g[b * SS + tid];
  double x2q = blockSum(xqv * xqv, red, tid);  // syncs cover xq/y2s writes

  // ---- pairwise hyperbolic distance row ----
  if (tid < SS) {
    double dot;
    SDOT(xq, khT, dot);
    double y2 = y2s[tid];
    double A = 1.0 - 2.0 * dot + y2;
    double Dn = fmax(1.0 - 2.0 * dot + x2q * y2, 1e-15);
    double Bc = 1.0 - x2q;
    double u2 = (A * A * x2q - 2.0 * A * Bc * dot + Bc * Bc * y2) / (Dn * Dn);
    double unr = sqrt(fmax(u2, 0.0));
    sA[tid] = 2.0 * atanh(fmin(unr, 1.0 - 1e-7));
  }
  double mind = reduceS_min(sA, red, tid);
  if (tid < SS) wun[tid] = exp(-(sA[tid] - mind));
  double wsum = reduceS_sum(wun, red, tid);
  if (tid < SS) wns[tid] = wun[tid] * (1.0 / (wsum + 1e-8));
  __syncthreads();

  // ---- fused: h = wns.v and mu_raw = wns.k (8+8 staged, 24 windows) ----
  double hreg, mu;
  {
    const float* vb_ = vB + tid;
    const float* kb_ = kB + tid;
    double h0=0.0,h1=0.0,h2=0.0,h3=0.0, m0=0.0,m1=0.0,m2=0.0,m3=0.0;
    for (int s0 = 0; s0 < SS; s0 += 8) {
      float v0 = vb_[(size_t)(s0 + 0) * DD];
      float v1 = vb_[(size_t)(s0 + 1) * DD];
      float v2 = vb_[(size_t)(s0 + 2) * DD];
      float v3 = vb_[(size_t)(s0 + 3) * DD];
      float v4 = vb_[(size_t)(s0 + 4) * DD];
      float v5 = vb_[(size_t)(s0 + 5) * DD];
      float v6 = vb_[(size_t)(s0 + 6) * DD];
      float v7 = vb_[(size_t)(s0 + 7) * DD];
      float k0 = kb_[(size_t)(s0 + 0) * DD];
      float k1 = kb_[(size_t)(s0 + 1) * DD];
      float k2 = kb_[(size_t)(s0 + 2) * DD];
      float k3 = kb_[(size_t)(s0 + 3) * DD];
      float k4 = kb_[(size_t)(s0 + 4) * DD];
      float k5 = kb_[(size_t)(s0 + 5) * DD];
      float k6 = kb_[(size_t)(s0 + 6) * DD];
      float k7 = kb_[(size_t)(s0 + 7) * DD];
      double w0 = wns[s0 + 0], w1 = wns[s0 + 1], w2 = wns[s0 + 2], w3 = wns[s0 + 3];
      double w4 = wns[s0 + 4], w5 = wns[s0 + 5], w6 = wns[s0 + 6], w7 = wns[s0 + 7];
      h0 += w0 * (double)v0; m0 += w0 * (double)k0;
      h1 += w1 * (double)v1; m1 += w1 * (double)k1;
      h2 += w2 * (double)v2; m2 += w2 * (double)k2;
      h3 += w3 * (double)v3; m3 += w3 * (double)k3;
      h0 += w4 * (double)v4; m0 += w4 * (double)k4;
      h1 += w5 * (double)v5; m1 += w5 * (double)k5;
      h2 += w6 * (double)v6; m2 += w6 * (double)k6;
      h3 += w7 * (double)v7; m3 += w7 * (double)k7;
    }
    hreg = (h0 + h1) + (h2 + h3);
    mu = (m0 + m1) + (m2 + m3);
  }

  // ---- mu0 = expmap0(clip_tangent(mu)) ----
  double x2c;
  {
    double n2 = blockSum(mu * mu, red, tid);
    double n = sqrt(n2);
    double cf = fmin(4.0 / (n + 1e-8), 1.0);
    double ncl = fmax(n * cf, 1e-15);
    double th = tanh(ncl);
    xc[tid] = mu * (th * cf / ncl);
    x2c = th * th;
  }
  __syncthreads();

  // ---- Karcher flow: 3 Riemannian SGD steps ----
  for (int it = 0; it < 3; ++it) {
    if (tid < SS) {
      double dot;
      SDOT(xc, khT, dot);
      double y2 = y2s[tid];
      double A = 1.0 - 2.0 * dot + y2;
      double Dn = fmax(1.0 - 2.0 * dot + x2c * y2, 1e-15);
      double Bc = 1.0 - x2c;
      double u2 = (A * A * x2c - 2.0 * A * Bc * dot + Bc * Bc * y2) / (Dn * Dn);
      double unr = sqrt(fmax(u2, 0.0));
      double un = fmax(unr, 1e-15);
      double coef = fmax(Bc, 1e-15) * atanh(fmin(un, 1.0 - 1e-7)) / un;
      double cs = wns[tid] * coef / Dn;
      sA[tid] = cs;
      sB[tid] = cs * A;
    }
    double S1 = reduceS_sum(sB, red, tid);   // syncs cover sA/sB writes
    double g;
    DSUM(sA, khB, g);
    double xold = xc[tid];
    double Bc = 1.0 - x2c;
    double vg = Bc * g - S1 * xold;           // v_grad[d]
    double nv2 = blockSum(vg * vg, red, tid);
    double nv = 0.1 * sqrt(nv2);
    double cf = fmin(4.0 / (nv + 1e-8), 1.0);
    double nw = fmax(nv * cf, 1e-15);
    double tsc = tanh(nw / fmax(Bc, 1e-15));
    double zco = tsc * 0.1 * cf / nw;
    double z = zco * vg;
    double xz = blockSum(xold * z, red, tid);
    double z2 = tsc * tsc;
    double den = fmax(1.0 + 2.0 * xz + x2c * z2, 1e-15);
    double a_ = 1.0 + 2.0 * xz + z2;
    double xnew = (a_ * xold + Bc * z) / den;
    // analytic ||xnew||^2 = (a^2 x2 + 2 a Bc <x,z> + Bc^2 z2) / den^2
    double x2new = (a_ * a_ * x2c + 2.0 * a_ * Bc * xz + Bc * Bc * z2) / (den * den);
    xc[tid] = xnew;
    x2c = x2new;
    __syncthreads();                          // covers xc write for next SDOT/DSUM
  }

  // ---- k_centroid = projx(mu + noise) ----
  {
    double cn = xc[tid] + noiseval;
    double n2 = blockSum(cn * cn, red, tid);
    double nn = sqrt(n2);
    double x2new = n2;
    if (nn > 1.0 - 1e-5) {               // uniform branch (nn is block-wide)
      double s = (1.0 - 1e-5) / fmax(nn, 1e-15);
      cn *= s;
      x2new = n2 * s * s;
    }
    xc[tid] = cn;
    x2c = x2new;
    __syncthreads();                          // covers xc write
  }

  // ---- c2k distances, entropy, variance; alf/bet for weighted_k ----
  if (tid < SS) {
    double dot;
    SDOT(xc, khT, dot);
    double y2 = y2s[tid];
    double A = 1.0 - 2.0 * dot + y2;
    double Dn = fmax(1.0 - 2.0 * dot + x2c * y2, 1e-15);
    double Bc = 1.0 - x2c;
    double u2 = (A * A * x2c - 2.0 * A * Bc * dot + Bc * Bc * y2) / (Dn * Dn);
    double unr = sqrt(fmax(u2, 0.0));
    double c2k = 2.0 * atanh(fmin(unr, 1.0 - 1e-7));
    sA[tid] = wns[tid] * c2k * c2k;
    sB[tid] = -wns[tid] * log(wns[tid] + 1e-8);
    double un = fmax(unr, 1e-15);
    double gl = fmax(Bc, 1e-15) * atanh(fmin(un, 1.0 - 1e-7)) / (un * Dn);
    double sq = sqrt(wun[tid] + 1e-8);
    alf[tid] = -sq * gl * A;
    bet[tid] = sq * gl * Bc;
  }
  double variance, entropy;
  reduceS_sum2(sA, sB, red, tid, variance, entropy);
  double tau = (double)tau_p[0];
  double tension = variance - tau * exp(entropy);

  // ---- power iteration on weighted_k (rank-structured) ----
  {
    double n2 = blockSum(vrndval * vrndval, red, tid);
    vr[tid] = vrndval / fmax(sqrt(n2), 1e-8);
  }
  for (int it = 0; it < 3; ++it) {
    double dxv = blockSum(xc[tid] * vr[tid], red, tid);  // syncs cover vr write
    if (tid < SS) {
      double dot;
      SDOT(vr, khT, dot);
      double pj = alf[tid] * dxv + bet[tid] * dot;
      sA[tid] = alf[tid] * pj;
      sB[tid] = bet[tid] * pj;
    }
    double T1 = reduceS_sum(sA, red, tid);
    double g;
    DSUM(sB, khB, g);
    double vnew = T1 * xc[tid] + g;
    double n2 = blockSum(vnew * vnew, red, tid);
    vr[tid] = vnew / fmax(sqrt(n2), 1e-8);
  }

  // ---- w_proj (fallback-norm fused with h-norm) ----
  double wproj, hn2;
  {
    double nq = fmax(sqrt(x2q), 1e-15);
    double aq = atanh(fmin(nq, 1.0 - 1e-7)) / nq;
    double nc = fmax(sqrt(x2c), 1e-15);
    double ac = atanh(fmin(nc, 1.0 - 1e-7)) / nc;
    double f = aq * xq[tid] - ac * xc[tid];
    double fn2;
    blockSum2(hreg * hreg, f * f, red, tid, hn2, fn2);
    double wg = vr[tid] / fmax(1.0 - x2c, 1e-15);
    double fb = f / fmax(sqrt(fn2), 1e-8);
    wproj = (variance > 1e-5) ? wg : fb;
  }

  // ---- h_comp, x, pitchfork RK4 ----
  double hn = sqrt(hn2);
  double hsc = asinh(hn) / (hn + 1e-8);
  double hc = hsc * hreg;
  double x = blockSum(hc * wproj, red, tid);
  double xi = (x == 0.0) ? odeval : x;
  const double dt = 0.5;
#pragma unroll
  for (int r = 0; r < 4; ++r) {
    double k1 = dt * (tension * xi - xi * xi * xi);
    double a2 = xi + 0.5 * k1;
    double k2 = dt * (tension * a2 - a2 * a2 * a2);
    double a3 = xi + 0.5 * k2;
    double k3 = dt * (tension * a3 - a3 * a3 * a3);
    double a4 = xi + k3;
    double k4 = dt * (tension * a4 - a4 * a4 * a4);
    xi += (k1 + 2.0 * k2 + 2.0 * k3 + k4) / 6.0;
  }
  double ts = (double)ts_p[0];
  double hp = (hc + (xi - x) * wproj) * ts;
  double hp2 = blockSum(hp * hp, red, tid);
  double nhp = sqrt(hp2);
  double cf = fmin(4.0 / (nhp + 1e-8), 1.0);
  double ncl = fmax(nhp * cf, 1e-15);
  double th = tanh(ncl);
  double nb = fmax(th, 1e-15);
  double ab = atanh(fmin(nb, 1.0 - 1e-7)) / nb;
  double hob = ab * th * cf / ncl * hp;
  double gate = fmax(tanh(tension / fmax(tau, 1e-3)), 0.0);

  // ---- fused output GEMM: out[row] = h_fused . Wo^T + bo ----
  hfl[tid] = (float)((1.0 - gate) * hreg + gate * hob);
  __syncthreads();
  double o = colDot(hfl, WoT, tid) + (double)bo[tid];
  out[rowOff + tid] = (float)o;
}

// ---------------- launch ----------------
extern "C" void kernel_launch(void* const* d_in, const int* in_sizes, int n_in,
                              void* d_out, int out_size, void* d_ws, size_t ws_size,
                              hipStream_t stream) {
  const float* q_in = (const float*)d_in[0];
  const float* k_in = (const float*)d_in[1];
  const float* v_in = (const float*)d_in[2];
  const float* Wq = (const float*)d_in[3];
  const float* bq = (const float*)d_in[4];
  const float* Wk = (const float*)d_in[5];
  const float* bk = (const float*)d_in[6];
  const float* Wv = (const float*)d_in[7];
  const float* bv = (const float*)d_in[8];
  const float* Wo = (const float*)d_in[9];
  const float* bo = (const float*)d_in[10];
  const float* tau = (const float*)d_in[11];
  const float* ts = (const float*)d_in[12];
  float* out = (float*)d_out;
  (void)in_sizes; (void)n_in; (void)out_size; (void)ws_size;

  char* base = (char*)d_ws;
  size_t off = 0;
  auto alloc = [&](size_t bytes) -> void* {
    void* p = base + off;
    off += (bytes + 255) & ~(size_t)255;
    return p;
  };
  float* WqT = (float*)alloc((size_t)DD * DD * 4);
  float* WkT = (float*)alloc((size_t)DD * DD * 4);
  float* WvT = (float*)alloc((size_t)DD * DD * 4);
  float* WoT = (float*)alloc((size_t)DD * DD * 4);
  float* kb = (float*)alloc((size_t)NE * 4);
  float* vb = (float*)alloc((size_t)NE * 4);
  float* qh = (float*)alloc((size_t)NE * 4);
  float* kh = (float*)alloc((size_t)NE * 4);
  float* khT = (float*)alloc((size_t)NE * 4);
  double* y2g = (double*)alloc((size_t)NROW * 8);

  hipLaunchKernelGGL(transpose4, dim3(4 * DD), dim3(DD), 0, stream,
                     Wq, Wk, Wv, Wo, WqT, WkT, WvT, WoT);
  hipLaunchKernelGGL(proj_kernel, dim3(NROW, 3), dim3(DD), 0, stream,
                     q_in, k_in, v_in, WqT, WkT, WvT, bq, bk, bv,
                     qh, kb, vb, kh, khT, y2g);
  hipLaunchKernelGGL(resonance_main, dim3(NROW), dim3(DD), 0, stream,
                     qh, kh, khT, kb, vb, y2g, WoT, bo, tau, ts, out);
}